// Round 3
// baseline (128.651 us; speedup 1.0000x reference)
//
#include <hip/hip_runtime.h>
#include <hip/hip_bf16.h>

// GMM NLL: N=524288 rows, P=16, G=8.
// R3: pure-VALU quad with V broadcast through SGPRs.
//   R1 was ds_read-issue-bound (LDS broadcast of V: 20480 ds ops/wave, 51us
//   model == 48.5us measured). R2's MFMA+shfl was latency-bound (52 VGPRs,
//   rematerialized fragments, 64 ds_bpermute/wave, MfmaUtil 3.4%).
//   Here: V_g is wave-uniform -> uniform-address loads compile to
//   s_load_dwordx* and feed v_fmac_f32 as the (free) scalar operand.
//   Work: 8 groups x (136 triangular FMA + 16 u-init + 16 square-FMA)
//   = ~1216 FMA/row -> 8.1us VALU floor at 157 TF. No LDS, no shfl except
//   the final block reduction.

#define P 16
#define G 8

// ws float layout (group stride 272):
//   g*272 + i*16 + j : V_g[i][j]   (L^{-1}, lower triangular, upper = 0)
//   g*272 + 256 + i  : u_g[i] = (V_g mu_g)[i]
#define GSTRIDE 272
#define WS_LC   (G * GSTRIDE)        // 2176: lcoef[G]
#define WS_LAM  (WS_LC + G)          // lam[P]
#define WS_LM1  (WS_LAM + P)         // lam-1[P]
#define WS_RL   (WS_LM1 + P)         // 1/lam[P]

__global__ __launch_bounds__(128) void gmm_prep(const float* __restrict__ lambdas,
                                                const float* __restrict__ mus,
                                                const float* __restrict__ sigmas,
                                                const float* __restrict__ w,
                                                float* __restrict__ ws,
                                                float* __restrict__ out) {
    __shared__ float Lsh[G][P][P];
    __shared__ float Vsh[G][P][P];
    __shared__ float ldet[G];
    const int tid = threadIdx.x;
    const int g = tid >> 4;
    const int r = tid & 15;

    float Srow[P], Lrow[P];
#pragma unroll
    for (int j = 0; j < P; ++j) Srow[j] = sigmas[g * P * P + r * P + j];

#pragma unroll
    for (int j = 0; j < P; ++j) {
        float s = Srow[j];
#pragma unroll
        for (int k = 0; k < P; ++k) {
            if (k < j) s -= Lrow[k] * Lsh[g][j][k];
        }
        if (r == j) {
            float dv = sqrtf(s);
            Lrow[j] = dv;
            Lsh[g][j][j] = dv;
        }
        __syncthreads();
        if (r > j) {
            float dv = s / Lsh[g][j][j];
            Lrow[j] = dv;
            Lsh[g][r][j] = dv;
        }
        __syncthreads();
    }

    if (r == 0) {
        float ld = 0.f;
#pragma unroll
        for (int j = 0; j < P; ++j) ld += __logf(Lsh[g][j][j]);
        ldet[g] = 2.0f * ld;
    }

    // invert L: thread r computes column r of V = L^{-1} (zeros above diag)
    float col[P];
#pragma unroll
    for (int i = 0; i < P; ++i) {
        float s = 0.f;
#pragma unroll
        for (int k = 0; k < P; ++k) {
            if (k < i) s += Lsh[g][i][k] * col[k];
        }
        float rii = 1.0f / Lsh[g][i][i];
        col[i] = (i == r) ? rii : -s * rii;
    }
#pragma unroll
    for (int i = 0; i < P; ++i) {
        Vsh[g][i][r] = col[i];
        ws[g * GSTRIDE + i * P + r] = col[i];   // column r of V_g
    }
    __syncthreads();

    // u_g[r] = (V_g mu_g)[r]
    float u = 0.f;
#pragma unroll
    for (int j = 0; j < P; ++j) u = fmaf(Vsh[g][r][j], mus[g * P + j], u);
    ws[g * GSTRIDE + 256 + r] = u;

    if (tid == 0) {
        float wm = w[0];
#pragma unroll
        for (int k = 1; k < G; ++k) wm = fmaxf(wm, w[k]);
        float s = 0.f;
#pragma unroll
        for (int k = 0; k < G; ++k) s += __expf(w[k] - wm);
        const float lse = wm + __logf(s);
        const float lead = -14.7030165f; // -0.5 * 16 * ln(2*pi)
#pragma unroll
        for (int k = 0; k < G; ++k)
            ws[WS_LC + k] = (w[k] - lse) + lead - 0.5f * ldet[k];
        out[0] = 0.f;   // replaces a separate memset launch
    }
    if (tid < P) {
        float lam = lambdas[tid];
        ws[WS_LAM + tid] = lam;
        ws[WS_LM1 + tid] = lam - 1.0f;
        ws[WS_RL  + tid] = 1.0f / lam;
    }
}

__global__ __launch_bounds__(256) void gmm_main(const float* __restrict__ X,
                                                const float* __restrict__ ws,
                                                float* __restrict__ out,
                                                int nrows) {
    __shared__ float red[4];

    const int tid  = threadIdx.x;
    const int lane = tid & 63;
    const int wid  = tid >> 6;

    const int row = blockIdx.x * 256 + tid;
    const int rclamp = row < nrows ? row : nrows - 1;
    const float4* Xv = (const float4*)(X + (size_t)rclamp * P);
    float4 q0 = Xv[0], q1 = Xv[1], q2 = Xv[2], q3 = Xv[3];
    float xv[P] = {q0.x, q0.y, q0.z, q0.w, q1.x, q1.y, q1.z, q1.w,
                   q2.x, q2.y, q2.z, q2.w, q3.x, q3.y, q3.z, q3.w};

    float xt[P];
    float jac = 0.f;
#pragma unroll
    for (int p = 0; p < P; ++p) {
        float ln = __logf(xv[p]);
        xt[p] = (__expf(ws[WS_LAM + p] * ln) - 1.0f) * ws[WS_RL + p];
        jac = fmaf(ln, ws[WS_LM1 + p], jac);
    }

    float mixed = 0.f;
#pragma unroll
    for (int g = 0; g < G; ++g) {
        const float* __restrict__ Vg = ws + g * GSTRIDE;  // wave-uniform -> SGPR
        float quad = 0.f;
#pragma unroll
        for (int i = 0; i < P; ++i) {
            float y = -Vg[256 + i];                        // -u_g[i]
#pragma unroll
            for (int j = 0; j <= i; ++j)
                y = fmaf(Vg[i * P + j], xt[j], y);         // scalar * vector FMA
            quad = fmaf(y, y, quad);
        }
        mixed += __expf(fmaf(-0.5f, quad, ws[WS_LC + g] + jac));
    }

    float nll = (row < nrows) ? -__logf(mixed) : 0.f;

#pragma unroll
    for (int off = 32; off > 0; off >>= 1) nll += __shfl_down(nll, off, 64);
    if (lane == 0) red[wid] = nll;
    __syncthreads();
    if (tid == 0) atomicAdd(out, red[0] + red[1] + red[2] + red[3]);
}

extern "C" void kernel_launch(void* const* d_in, const int* in_sizes, int n_in,
                              void* d_out, int out_size, void* d_ws, size_t ws_size,
                              hipStream_t stream) {
    const float* X       = (const float*)d_in[0];
    const float* lambdas = (const float*)d_in[1];
    const float* mus     = (const float*)d_in[2];
    const float* sigmas  = (const float*)d_in[3];
    const float* w       = (const float*)d_in[4];
    float* out = (float*)d_out;
    float* ws  = (float*)d_ws;

    const int nrows = in_sizes[0] / P;   // 524288

    gmm_prep<<<1, 128, 0, stream>>>(lambdas, mus, sigmas, w, ws, out);
    gmm_main<<<(nrows + 255) / 256, 256, 0, stream>>>(X, ws, out, nrows);
}